// Round 2
// baseline (9513.825 us; speedup 1.0000x reference)
//
#include <hip/hip_runtime.h>
#include <hip/hip_fp16.h>

#define B_ 256
#define S_ 512
#define D_ 200
#define H_ 256

typedef _Float16 half2_t __attribute__((ext_vector_type(2)));
typedef _Float16 half8_t __attribute__((ext_vector_type(8)));
typedef float    floatx4 __attribute__((ext_vector_type(4)));
typedef unsigned int u32x16 __attribute__((ext_vector_type(16)));

__device__ __forceinline__ float fdot2f(half2_t a, half2_t b, float c) {
#if __has_builtin(__builtin_amdgcn_fdot2)
    return __builtin_amdgcn_fdot2(a, b, c, false);
#else
    return c + (float)a[0] * (float)b[0] + (float)a[1] * (float)b[1];
#endif
}

__device__ __forceinline__ half2_t bc_h2(unsigned int u) {
    return __builtin_bit_cast(half2_t, u);
}

__device__ __forceinline__ float fast_sig(float x) {
    return 1.f / (1.f + __expf(-x));
}
__device__ __forceinline__ float fast_tanh(float x) {
    x = fminf(15.f, fmaxf(-15.f, x));
    float e = __expf(2.f * x);
    return (e - 1.f) / (e + 1.f);
}

// ---------------------------------------------------------------------------
// prep: build fp16 weight layouts in workspace.
//   W4T [1024][224]: W4T[n][k] = Wg[k][j] (x-part rows 0..199, zero-padded)
//   WhT [1024][256]: WhT[n][k] = Wg[200+k][j] (h-part), n = g*256+j
// ---------------------------------------------------------------------------
__global__ void prep(const float* __restrict__ Wi, const float* __restrict__ Wf,
                     const float* __restrict__ Wo, const float* __restrict__ Wz,
                     _Float16* __restrict__ W4T, _Float16* __restrict__ WhT) {
    const int n = blockIdx.x;      // 0..1023
    const int t = threadIdx.x;     // 0..255
    const int g = n >> 8, j = n & 255;
    const float* Wg = (g == 0) ? Wi : (g == 1) ? Wf : (g == 2) ? Wo : Wz;
    if (t < 224)
        W4T[(size_t)n * 224 + t] = (t < D_) ? (_Float16)Wg[t * 256 + j] : (_Float16)0.f;
    WhT[(size_t)n * 256 + t] = (_Float16)Wg[(D_ + t) * 256 + j];
}

// ---------------------------------------------------------------------------
// gemm_x: G[m][n] = sum_k X[m][k] * W4T[n][k]  (fp16 MFMA 16x16x32, 128x128)
// ---------------------------------------------------------------------------
__global__ __launch_bounds__(256) void gemm_x(const float* __restrict__ X,
                                              const _Float16* __restrict__ W4T,
                                              _Float16* __restrict__ G) {
    __shared__ __align__(16) _Float16 As[128][40];
    __shared__ __align__(16) _Float16 Bs[128][40];

    const int mt = blockIdx.x >> 3;
    const int nt = blockIdx.x & 7;
    const int m0 = mt * 128, n0 = nt * 128;
    const int tid  = threadIdx.x;
    const int lane = tid & 63, wave = tid >> 6;
    const int quad = lane >> 4, l16 = lane & 15;
    const int mq = (wave & 1) * 64, nq = (wave >> 1) * 64;

    floatx4 acc[4][4];
#pragma unroll
    for (int i = 0; i < 4; ++i)
#pragma unroll
        for (int j = 0; j < 4; ++j) acc[i][j] = (floatx4){0.f, 0.f, 0.f, 0.f};

    const int srow = tid >> 1;
    const int koff = (tid & 1) * 16;

    for (int kt = 0; kt < 7; ++kt) {
        const int k0 = kt * 32;
        {
            const int m = m0 + srow;
            const float* xr = X + (size_t)m * D_ + (k0 + koff);
            half8_t v0, v1;
            if (m < B_ * S_ - 1) {
                const floatx4* xp = (const floatx4*)xr;
                floatx4 f0 = xp[0], f1 = xp[1], f2 = xp[2], f3 = xp[3];
#pragma unroll
                for (int i = 0; i < 4; ++i) {
                    v0[i]     = (_Float16)f0[i];
                    v0[4 + i] = (_Float16)f1[i];
                    v1[i]     = (_Float16)f2[i];
                    v1[4 + i] = (_Float16)f3[i];
                }
            } else {
#pragma unroll
                for (int i = 0; i < 8; ++i) {
                    int k = k0 + koff + i;
                    v0[i] = (k < D_) ? (_Float16)xr[i] : (_Float16)0.f;
                }
#pragma unroll
                for (int i = 0; i < 8; ++i) {
                    int k = k0 + koff + 8 + i;
                    v1[i] = (k < D_) ? (_Float16)xr[8 + i] : (_Float16)0.f;
                }
            }
            *(half8_t*)&As[srow][koff]     = v0;
            *(half8_t*)&As[srow][koff + 8] = v1;
        }
        {
            const _Float16* wr = W4T + (size_t)(n0 + srow) * 224 + (k0 + koff);
            const half8_t* wp = (const half8_t*)wr;
            *(half8_t*)&Bs[srow][koff]     = wp[0];
            *(half8_t*)&Bs[srow][koff + 8] = wp[1];
        }
        __syncthreads();

        half8_t af[4], bf[4];
#pragma unroll
        for (int i = 0; i < 4; ++i) af[i] = *(const half8_t*)&As[mq + i * 16 + l16][quad * 8];
#pragma unroll
        for (int i = 0; i < 4; ++i) bf[i] = *(const half8_t*)&Bs[nq + i * 16 + l16][quad * 8];
#pragma unroll
        for (int mi = 0; mi < 4; ++mi)
#pragma unroll
            for (int ni = 0; ni < 4; ++ni)
                acc[mi][ni] = __builtin_amdgcn_mfma_f32_16x16x32_f16(af[mi], bf[ni], acc[mi][ni], 0, 0, 0);
        __syncthreads();
    }

#pragma unroll
    for (int mi = 0; mi < 4; ++mi)
#pragma unroll
        for (int ni = 0; ni < 4; ++ni)
#pragma unroll
            for (int r = 0; r < 4; ++r) {
                int grow = m0 + mq + mi * 16 + quad * 4 + r;
                int gcol = n0 + nq + ni * 16 + l16;
                G[(size_t)grow * 1024 + gcol] = (_Float16)acc[mi][ni][r];
            }
}

// ---------------------------------------------------------------------------
// lstm_rec: one workgroup (512 threads) per batch row.
// Thread t owns gate columns t (i|f) and t+512 (o|z).
// Wh k in [0,192): register-resident as 12 named u32x16 SSA vectors (192 VGPR).
// Wh k in [192,256): LDS (128 KB), conflict-free half8 layout WL[c][col].
// h broadcast per step via LDS b128; all-fp32 gate math.
// ---------------------------------------------------------------------------
__global__ __launch_bounds__(512, 2) void lstm_rec(
    const _Float16* __restrict__ G,     // [B][S][1024] fp16
    const _Float16* __restrict__ WhT,   // [1024][256] fp16
    const float* __restrict__ bi, const float* __restrict__ bfg,
    const float* __restrict__ bo, const float* __restrict__ bz,
    const float* __restrict__ mask,     // [B][S] fp32
    float* __restrict__ out)            // [B][256] fp32
{
    extern __shared__ __align__(16) char smem[];
    _Float16* WL   = (_Float16*)smem;                    // 8*1024*8 halfs = 128 KB
    float*    pre  = (float*)(smem + 131072);            // 4 KB
    _Float16* hbuf = (_Float16*)(smem + 131072 + 4096);  // 512 B

    const int b  = blockIdx.x;
    const int t  = threadIdx.x;   // 0..511
    const int n1 = t + 512;

    // ---- stage LDS weight slice: WL[c][col] = WhT[col][192 + c*8 .. +7] ----
    {
        half8_t* WL8 = (half8_t*)WL;
        for (int idx = t; idx < 8192; idx += 512) {
            const int c = idx >> 10, col = idx & 1023;
            WL8[idx] = *(const half8_t*)(WhT + (size_t)col * 256 + 192 + c * 8);
        }
    }
    // ---- register-resident weight slice: k in [0,192), 96 dwords per column ----
    const u32x16* pw0 = (const u32x16*)(WhT + (size_t)t  * 256);
    const u32x16* pw1 = (const u32x16*)(WhT + (size_t)n1 * 256);
    u32x16 wa0 = pw0[0], wa1 = pw0[1], wa2 = pw0[2], wa3 = pw0[3], wa4 = pw0[4], wa5 = pw0[5];
    u32x16 wb0 = pw1[0], wb1 = pw1[1], wb2 = pw1[2], wb3 = pw1[3], wb4 = pw1[4], wb5 = pw1[5];

    const float bias0 = (t < 256) ? bi[t] : bfg[t - 256];
    const float bias1 = (t < 256) ? bo[t] : bz[t - 256];

    if (t < 256) hbuf[t] = (_Float16)0.f;
    __syncthreads();

    float c = 0.f, acc = 0.f, msum = 0.f;
    const _Float16* Gb = G + (size_t)b * S_ * 1024;
    const float*    mb = mask + (size_t)b * S_;
    const half8_t*  WL8 = (const half8_t*)WL;

#define CHUNK(HOFF, WA, WB, IA) do {                                   \
        half8_t hv = *(const half8_t*)(hbuf + (HOFF));                 \
        half2_t h0 = {hv[0], hv[1]}, h1 = {hv[2], hv[3]};              \
        half2_t h2 = {hv[4], hv[5]}, h3 = {hv[6], hv[7]};              \
        a0 = fdot2f(h0, bc_h2((WA)[(IA) + 0]), a0);                    \
        a1 = fdot2f(h1, bc_h2((WA)[(IA) + 1]), a1);                    \
        a2 = fdot2f(h2, bc_h2((WA)[(IA) + 2]), a2);                    \
        a3 = fdot2f(h3, bc_h2((WA)[(IA) + 3]), a3);                    \
        d0 = fdot2f(h0, bc_h2((WB)[(IA) + 0]), d0);                    \
        d1 = fdot2f(h1, bc_h2((WB)[(IA) + 1]), d1);                    \
        d2 = fdot2f(h2, bc_h2((WB)[(IA) + 2]), d2);                    \
        d3 = fdot2f(h3, bc_h2((WB)[(IA) + 3]), d3);                    \
    } while (0)

#define LCHUNK(C) do {                                                 \
        half8_t hv = *(const half8_t*)(hbuf + 192 + (C) * 8);          \
        half8_t w0 = WL8[(C) * 1024 + t];                              \
        half8_t w1 = WL8[(C) * 1024 + t + 512];                       \
        a0 = fdot2f((half2_t){hv[0], hv[1]}, (half2_t){w0[0], w0[1]}, a0); \
        a1 = fdot2f((half2_t){hv[2], hv[3]}, (half2_t){w0[2], w0[3]}, a1); \
        a2 = fdot2f((half2_t){hv[4], hv[5]}, (half2_t){w0[4], w0[5]}, a2); \
        a3 = fdot2f((half2_t){hv[6], hv[7]}, (half2_t){w0[6], w0[7]}, a3); \
        d0 = fdot2f((half2_t){hv[0], hv[1]}, (half2_t){w1[0], w1[1]}, d0); \
        d1 = fdot2f((half2_t){hv[2], hv[3]}, (half2_t){w1[2], w1[3]}, d1); \
        d2 = fdot2f((half2_t){hv[4], hv[5]}, (half2_t){w1[4], w1[5]}, d2); \
        d3 = fdot2f((half2_t){hv[6], hv[7]}, (half2_t){w1[6], w1[7]}, d3); \
    } while (0)

    for (int s = 0; s < S_; ++s) {
        // issue global loads early; consumed ~1000 cycles later
        const float g0 = (float)Gb[(size_t)s * 1024 + t];
        const float g1 = (float)Gb[(size_t)s * 1024 + n1];
        const float m  = mb[s];

        float a0 = 0.f, a1 = 0.f, a2 = 0.f, a3 = 0.f;
        float d0 = 0.f, d1 = 0.f, d2 = 0.f, d3 = 0.f;

        CHUNK(  0, wa0, wb0,  0); CHUNK(  8, wa0, wb0,  4);
        CHUNK( 16, wa0, wb0,  8); CHUNK( 24, wa0, wb0, 12);
        CHUNK( 32, wa1, wb1,  0); CHUNK( 40, wa1, wb1,  4);
        CHUNK( 48, wa1, wb1,  8); CHUNK( 56, wa1, wb1, 12);
        CHUNK( 64, wa2, wb2,  0); CHUNK( 72, wa2, wb2,  4);
        CHUNK( 80, wa2, wb2,  8); CHUNK( 88, wa2, wb2, 12);
        CHUNK( 96, wa3, wb3,  0); CHUNK(104, wa3, wb3,  4);
        CHUNK(112, wa3, wb3,  8); CHUNK(120, wa3, wb3, 12);
        CHUNK(128, wa4, wb4,  0); CHUNK(136, wa4, wb4,  4);
        CHUNK(144, wa4, wb4,  8); CHUNK(152, wa4, wb4, 12);
        CHUNK(160, wa5, wb5,  0); CHUNK(168, wa5, wb5,  4);
        CHUNK(176, wa5, wb5,  8); CHUNK(184, wa5, wb5, 12);
        LCHUNK(0); LCHUNK(1); LCHUNK(2); LCHUNK(3);
        LCHUNK(4); LCHUNK(5); LCHUNK(6); LCHUNK(7);

        const float p0 = bias0 + g0 + ((a0 + a1) + (a2 + a3));
        const float p1 = bias1 + g1 + ((d0 + d1) + (d2 + d3));
        // spread transcendentals across all 512 threads:
        // t<256: p0 = gate i -> sig, p1 = gate o -> sig
        // t>=256: p0 = gate f -> sig, p1 = gate z -> tanh
        const float v0 = fast_sig(p0);
        const float v1 = (t < 256) ? fast_sig(p1) : fast_tanh(p1);
        pre[t]  = v0;
        pre[n1] = v1;
        __syncthreads();
        if (t < 256) {
            const float fi = v0;            // sig(i)
            const float fo = v1;            // sig(o)
            const float ff = pre[256 + t];  // sig(f)
            const float fz = pre[768 + t];  // tanh(z)
            c = fi * fz + ff * c;
            const float h = fo * fast_tanh(c);
            acc  += m * h;
            msum += m;
            hbuf[t] = (_Float16)h;
        }
        __syncthreads();
    }
#undef CHUNK
#undef LCHUNK
    if (t < 256) out[b * 256 + t] = acc / msum;
}

extern "C" void kernel_launch(void* const* d_in, const int* in_sizes, int n_in,
                              void* d_out, int out_size, void* d_ws, size_t ws_size,
                              hipStream_t stream) {
    const float* X    = (const float*)d_in[0];
    const float* mask = (const float*)d_in[1];
    const float* Wi   = (const float*)d_in[2];
    const float* bi   = (const float*)d_in[3];
    const float* Wf   = (const float*)d_in[4];
    const float* bf   = (const float*)d_in[5];
    const float* Wo   = (const float*)d_in[6];
    const float* bo   = (const float*)d_in[7];
    const float* Wz   = (const float*)d_in[8];
    const float* bz   = (const float*)d_in[9];
    float* out = (float*)d_out;

    char* ws = (char*)d_ws;
    _Float16* G   = (_Float16*)ws;                                   // 268,435,456 B
    _Float16* W4T = (_Float16*)(ws + (size_t)B_ * S_ * 1024 * 2);    //     458,752 B
    _Float16* WhT = (_Float16*)(ws + (size_t)B_ * S_ * 1024 * 2 + (size_t)1024 * 224 * 2);

    hipLaunchKernelGGL(prep,     dim3(1024), dim3(256), 0, stream, Wi, Wf, Wo, Wz, W4T, WhT);
    hipLaunchKernelGGL(gemm_x,   dim3(8192), dim3(256), 0, stream, X, W4T, G);
    hipLaunchKernelGGL(lstm_rec, dim3(B_),   dim3(512), 131072 + 4096 + 512, stream,
                       G, WhT, bi, bf, bo, bz, mask, out);
}

// Round 3
// 3161.782 us; speedup vs baseline: 3.0090x; 3.0090x over previous
//
#include <hip/hip_runtime.h>
#include <hip/hip_fp16.h>

#define B_ 256
#define S_ 512
#define D_ 200
#define H_ 256

typedef _Float16 half2_t __attribute__((ext_vector_type(2)));
typedef _Float16 half8_t __attribute__((ext_vector_type(8)));
typedef float    floatx4 __attribute__((ext_vector_type(4)));
typedef unsigned int u32x4 __attribute__((ext_vector_type(4)));

__device__ __forceinline__ float fdot2f(half2_t a, half2_t b, float c) {
#if __has_builtin(__builtin_amdgcn_fdot2)
    return __builtin_amdgcn_fdot2(a, b, c, false);
#else
    return c + (float)a[0] * (float)b[0] + (float)a[1] * (float)b[1];
#endif
}

__device__ __forceinline__ half2_t bc_h2(unsigned int u) {
    return __builtin_bit_cast(half2_t, u);
}

__device__ __forceinline__ float fast_sig(float x) {
    return 1.f / (1.f + __expf(-x));
}
__device__ __forceinline__ float fast_tanh(float x) {
    x = fminf(15.f, fmaxf(-15.f, x));
    float e = __expf(2.f * x);
    return (e - 1.f) / (e + 1.f);
}

// ---------------------------------------------------------------------------
// prep: build fp16 weight layouts in workspace.
//   W4T [1024][224]: W4T[n][k] = Wg[k][j] (x-part rows 0..199, zero-padded)
//   WhT [1024][256]: WhT[n][k] = Wg[200+k][j] (h-part), n = g*256+j
// ---------------------------------------------------------------------------
__global__ void prep(const float* __restrict__ Wi, const float* __restrict__ Wf,
                     const float* __restrict__ Wo, const float* __restrict__ Wz,
                     _Float16* __restrict__ W4T, _Float16* __restrict__ WhT) {
    const int n = blockIdx.x;      // 0..1023
    const int t = threadIdx.x;     // 0..255
    const int g = n >> 8, j = n & 255;
    const float* Wg = (g == 0) ? Wi : (g == 1) ? Wf : (g == 2) ? Wo : Wz;
    if (t < 224)
        W4T[(size_t)n * 224 + t] = (t < D_) ? (_Float16)Wg[t * 256 + j] : (_Float16)0.f;
    WhT[(size_t)n * 256 + t] = (_Float16)Wg[(D_ + t) * 256 + j];
}

// ---------------------------------------------------------------------------
// gemm_x: G[m][n] = sum_k X[m][k] * W4T[n][k]  (fp16 MFMA 16x16x32, 128x128)
// ---------------------------------------------------------------------------
__global__ __launch_bounds__(256) void gemm_x(const float* __restrict__ X,
                                              const _Float16* __restrict__ W4T,
                                              _Float16* __restrict__ G) {
    __shared__ __align__(16) _Float16 As[128][40];
    __shared__ __align__(16) _Float16 Bs[128][40];

    const int mt = blockIdx.x >> 3;
    const int nt = blockIdx.x & 7;
    const int m0 = mt * 128, n0 = nt * 128;
    const int tid  = threadIdx.x;
    const int lane = tid & 63, wave = tid >> 6;
    const int quad = lane >> 4, l16 = lane & 15;
    const int mq = (wave & 1) * 64, nq = (wave >> 1) * 64;

    floatx4 acc[4][4];
#pragma unroll
    for (int i = 0; i < 4; ++i)
#pragma unroll
        for (int j = 0; j < 4; ++j) acc[i][j] = (floatx4){0.f, 0.f, 0.f, 0.f};

    const int srow = tid >> 1;
    const int koff = (tid & 1) * 16;

    for (int kt = 0; kt < 7; ++kt) {
        const int k0 = kt * 32;
        {
            const int m = m0 + srow;
            const float* xr = X + (size_t)m * D_ + (k0 + koff);
            half8_t v0, v1;
            if (m < B_ * S_ - 1) {
                const floatx4* xp = (const floatx4*)xr;
                floatx4 f0 = xp[0], f1 = xp[1], f2 = xp[2], f3 = xp[3];
#pragma unroll
                for (int i = 0; i < 4; ++i) {
                    v0[i]     = (_Float16)f0[i];
                    v0[4 + i] = (_Float16)f1[i];
                    v1[i]     = (_Float16)f2[i];
                    v1[4 + i] = (_Float16)f3[i];
                }
            } else {
#pragma unroll
                for (int i = 0; i < 8; ++i) {
                    int k = k0 + koff + i;
                    v0[i] = (k < D_) ? (_Float16)xr[i] : (_Float16)0.f;
                }
#pragma unroll
                for (int i = 0; i < 8; ++i) {
                    int k = k0 + koff + 8 + i;
                    v1[i] = (k < D_) ? (_Float16)xr[8 + i] : (_Float16)0.f;
                }
            }
            *(half8_t*)&As[srow][koff]     = v0;
            *(half8_t*)&As[srow][koff + 8] = v1;
        }
        {
            const _Float16* wr = W4T + (size_t)(n0 + srow) * 224 + (k0 + koff);
            const half8_t* wp = (const half8_t*)wr;
            *(half8_t*)&Bs[srow][koff]     = wp[0];
            *(half8_t*)&Bs[srow][koff + 8] = wp[1];
        }
        __syncthreads();

        half8_t af[4], bf[4];
#pragma unroll
        for (int i = 0; i < 4; ++i) af[i] = *(const half8_t*)&As[mq + i * 16 + l16][quad * 8];
#pragma unroll
        for (int i = 0; i < 4; ++i) bf[i] = *(const half8_t*)&Bs[nq + i * 16 + l16][quad * 8];
#pragma unroll
        for (int mi = 0; mi < 4; ++mi)
#pragma unroll
            for (int ni = 0; ni < 4; ++ni)
                acc[mi][ni] = __builtin_amdgcn_mfma_f32_16x16x32_f16(af[mi], bf[ni], acc[mi][ni], 0, 0, 0);
        __syncthreads();
    }

#pragma unroll
    for (int mi = 0; mi < 4; ++mi)
#pragma unroll
        for (int ni = 0; ni < 4; ++ni)
#pragma unroll
            for (int r = 0; r < 4; ++r) {
                int grow = m0 + mq + mi * 16 + quad * 4 + r;
                int gcol = n0 + nq + ni * 16 + l16;
                G[(size_t)grow * 1024 + gcol] = (_Float16)acc[mi][ni][r];
            }
}

// ---------------------------------------------------------------------------
// lstm_rec: one workgroup (1024 threads = 16 waves) per batch row.
// Thread t owns gate-column n = t (gate g = t>>8, unit j = t&255).
// Wh k in [0,192): 96 pinned scalar VGPRs per thread (asm "+v" prevents the
//   allocator from sinking the loads into the loop — the round-2 failure).
// Wh k in [192,256): LDS, 128 KB, contiguous half8 layout WL8[c*1024 + col].
// 1024 threads => 16 waves => 4 waves/SIMD => 128-VGPR cap is the natural
// allocation; demand = 96 weights + ~25 working regs = fits without spill.
// ---------------------------------------------------------------------------
__global__ __launch_bounds__(1024) void lstm_rec(
    const _Float16* __restrict__ G,     // [B][S][1024] fp16
    const _Float16* __restrict__ WhT,   // [1024][256] fp16
    const float* __restrict__ bi, const float* __restrict__ bfg,
    const float* __restrict__ bo, const float* __restrict__ bz,
    const float* __restrict__ mask,     // [B][S] fp32
    float* __restrict__ out)            // [B][256] fp32
{
    extern __shared__ __align__(16) char smem[];
    _Float16* WL   = (_Float16*)smem;                    // 128 KB
    float*    act  = (float*)(smem + 131072);            // 4 KB
    _Float16* hbuf = (_Float16*)(smem + 131072 + 4096);  // 512 B

    const int b    = blockIdx.x;
    const int t    = threadIdx.x;   // 0..1023 == gate-column
    const int gate = t >> 8;

    // ---- stage LDS weight slice: WL8[c*1024 + t] = WhT[t][192+8c .. +7] ----
    half8_t* WL8 = (half8_t*)WL;
    {
        const half8_t* wsrc = (const half8_t*)(WhT + (size_t)t * 256 + 192);
#pragma unroll
        for (int i = 0; i < 8; ++i) WL8[i * 1024 + t] = wsrc[i];
    }

    // ---- register weight slice: k in [0,192) = 96 dwords, pinned ----
    const u32x4* pw = (const u32x4*)(WhT + (size_t)t * 256);
#define DECLW(i) unsigned w##i##_0, w##i##_1, w##i##_2, w##i##_3
#define LOADW(i) do { u32x4 _tmp = pw[i];                                     \
        w##i##_0 = _tmp[0]; w##i##_1 = _tmp[1];                               \
        w##i##_2 = _tmp[2]; w##i##_3 = _tmp[3];                               \
        asm volatile("" : "+v"(w##i##_0), "+v"(w##i##_1),                     \
                          "+v"(w##i##_2), "+v"(w##i##_3)); } while (0)
    DECLW(0);  DECLW(1);  DECLW(2);  DECLW(3);  DECLW(4);  DECLW(5);
    DECLW(6);  DECLW(7);  DECLW(8);  DECLW(9);  DECLW(10); DECLW(11);
    DECLW(12); DECLW(13); DECLW(14); DECLW(15); DECLW(16); DECLW(17);
    DECLW(18); DECLW(19); DECLW(20); DECLW(21); DECLW(22); DECLW(23);
    LOADW(0);  LOADW(1);  LOADW(2);  LOADW(3);  LOADW(4);  LOADW(5);
    LOADW(6);  LOADW(7);  LOADW(8);  LOADW(9);  LOADW(10); LOADW(11);
    LOADW(12); LOADW(13); LOADW(14); LOADW(15); LOADW(16); LOADW(17);
    LOADW(18); LOADW(19); LOADW(20); LOADW(21); LOADW(22); LOADW(23);

    const float bias = ((gate == 0) ? bi : (gate == 1) ? bfg
                        : (gate == 2) ? bo : bz)[t & 255];

    if (t < 256) hbuf[t] = (_Float16)0.f;
    __syncthreads();

    float c = 0.f, acc = 0.f, msum = 0.f;
    const _Float16* Gb = G + (size_t)b * S_ * 1024;
    const float*    mb = mask + (size_t)b * S_;

#define RCHUNK(i) do {                                                        \
        half8_t hv = *(const half8_t*)(hbuf + (i) * 8);                       \
        a0 = fdot2f((half2_t){hv[0], hv[1]}, bc_h2(w##i##_0), a0);            \
        a1 = fdot2f((half2_t){hv[2], hv[3]}, bc_h2(w##i##_1), a1);            \
        a2 = fdot2f((half2_t){hv[4], hv[5]}, bc_h2(w##i##_2), a2);            \
        a3 = fdot2f((half2_t){hv[6], hv[7]}, bc_h2(w##i##_3), a3);            \
    } while (0)
#define LCHUNK(C) do {                                                        \
        half8_t hv = *(const half8_t*)(hbuf + 192 + (C) * 8);                 \
        half8_t wv = WL8[(C) * 1024 + t];                                     \
        a0 = fdot2f((half2_t){hv[0], hv[1]}, (half2_t){wv[0], wv[1]}, a0);    \
        a1 = fdot2f((half2_t){hv[2], hv[3]}, (half2_t){wv[2], wv[3]}, a1);    \
        a2 = fdot2f((half2_t){hv[4], hv[5]}, (half2_t){wv[4], wv[5]}, a2);    \
        a3 = fdot2f((half2_t){hv[6], hv[7]}, (half2_t){wv[6], wv[7]}, a3);    \
    } while (0)

    for (int s = 0; s < S_; ++s) {
        // issue global loads early; consumed ~1000 cycles later
        const float g0 = (float)Gb[((size_t)s << 10) + t];
        const float m  = mb[s];

        float a0 = 0.f, a1 = 0.f, a2 = 0.f, a3 = 0.f;
        RCHUNK(0);  RCHUNK(1);  RCHUNK(2);  RCHUNK(3);  RCHUNK(4);  RCHUNK(5);
        RCHUNK(6);  RCHUNK(7);  RCHUNK(8);  RCHUNK(9);  RCHUNK(10); RCHUNK(11);
        RCHUNK(12); RCHUNK(13); RCHUNK(14); RCHUNK(15); RCHUNK(16); RCHUNK(17);
        RCHUNK(18); RCHUNK(19); RCHUNK(20); RCHUNK(21); RCHUNK(22); RCHUNK(23);
        LCHUNK(0); LCHUNK(1); LCHUNK(2); LCHUNK(3);
        LCHUNK(4); LCHUNK(5); LCHUNK(6); LCHUNK(7);

        const float p = bias + g0 + ((a0 + a1) + (a2 + a3));
        // one transcendental per thread: gates i,f,o -> sigmoid; z -> tanh
        const float v = (gate < 3) ? fast_sig(p) : fast_tanh(p);
        act[t] = v;
        __syncthreads();
        if (t < 256) {
            const float fi = v;             // own value: sig(i)
            const float ff = act[256 + t];  // sig(f)
            const float fo = act[512 + t];  // sig(o)
            const float fz = act[768 + t];  // tanh(z)
            c = fi * fz + ff * c;
            const float h = fo * fast_tanh(c);
            acc  += m * h;
            msum += m;
            hbuf[t] = (_Float16)h;
        }
        __syncthreads();
    }
#undef RCHUNK
#undef LCHUNK
#undef DECLW
#undef LOADW
    if (t < 256) out[b * 256 + t] = acc / msum;
}

extern "C" void kernel_launch(void* const* d_in, const int* in_sizes, int n_in,
                              void* d_out, int out_size, void* d_ws, size_t ws_size,
                              hipStream_t stream) {
    const float* X    = (const float*)d_in[0];
    const float* mask = (const float*)d_in[1];
    const float* Wi   = (const float*)d_in[2];
    const float* bi   = (const float*)d_in[3];
    const float* Wf   = (const float*)d_in[4];
    const float* bf   = (const float*)d_in[5];
    const float* Wo   = (const float*)d_in[6];
    const float* bo   = (const float*)d_in[7];
    const float* Wz   = (const float*)d_in[8];
    const float* bz   = (const float*)d_in[9];
    float* out = (float*)d_out;

    char* ws = (char*)d_ws;
    _Float16* G   = (_Float16*)ws;                                   // 268,435,456 B
    _Float16* W4T = (_Float16*)(ws + (size_t)B_ * S_ * 1024 * 2);    //     458,752 B
    _Float16* WhT = (_Float16*)(ws + (size_t)B_ * S_ * 1024 * 2 + (size_t)1024 * 224 * 2);

    hipLaunchKernelGGL(prep,     dim3(1024), dim3(256), 0, stream, Wi, Wf, Wo, Wz, W4T, WhT);
    hipLaunchKernelGGL(gemm_x,   dim3(8192), dim3(256), 0, stream, X, W4T, G);
    hipLaunchKernelGGL(lstm_rec, dim3(B_),   dim3(1024), 131072 + 4096 + 512, stream,
                       G, WhT, bi, bf, bo, bz, mask, out);
}

// Round 4
// 1763.281 us; speedup vs baseline: 5.3955x; 1.7931x over previous
//
#include <hip/hip_runtime.h>
#include <hip/hip_fp16.h>

#define B_ 256
#define S_ 512
#define D_ 200
#define H_ 256

typedef _Float16 half2_t __attribute__((ext_vector_type(2)));
typedef _Float16 half8_t __attribute__((ext_vector_type(8)));
typedef float    floatx4 __attribute__((ext_vector_type(4)));
typedef unsigned int u32x4 __attribute__((ext_vector_type(4)));
typedef unsigned int u32x2 __attribute__((ext_vector_type(2)));

__device__ __forceinline__ float fdot2f(half2_t a, half2_t b, float c) {
#if __has_builtin(__builtin_amdgcn_fdot2)
    return __builtin_amdgcn_fdot2(a, b, c, false);
#else
    return c + (float)a[0] * (float)b[0] + (float)a[1] * (float)b[1];
#endif
}

__device__ __forceinline__ half2_t bc_h2(unsigned int u) {
    return __builtin_bit_cast(half2_t, u);
}

__device__ __forceinline__ float fast_sig(float x) {
    return 1.f / (1.f + __expf(-x));
}
__device__ __forceinline__ float fast_tanh(float x) {
    x = fminf(15.f, fmaxf(-15.f, x));
    float e = __expf(2.f * x);
    return (e - 1.f) / (e + 1.f);
}

// ---------------------------------------------------------------------------
// prep: build fp16 weight layouts in workspace.
//   W4T [1024][224]: W4T[n][k] = Wg[k][j] (x-part rows 0..199, zero-padded)
//   WhT [1024][256]: WhT[n][k] = Wg[200+k][j] (h-part), n = g*256+j
// ---------------------------------------------------------------------------
__global__ void prep(const float* __restrict__ Wi, const float* __restrict__ Wf,
                     const float* __restrict__ Wo, const float* __restrict__ Wz,
                     _Float16* __restrict__ W4T, _Float16* __restrict__ WhT) {
    const int n = blockIdx.x;      // 0..1023
    const int t = threadIdx.x;     // 0..255
    const int g = n >> 8, j = n & 255;
    const float* Wg = (g == 0) ? Wi : (g == 1) ? Wf : (g == 2) ? Wo : Wz;
    if (t < 224)
        W4T[(size_t)n * 224 + t] = (t < D_) ? (_Float16)Wg[t * 256 + j] : (_Float16)0.f;
    WhT[(size_t)n * 256 + t] = (_Float16)Wg[(D_ + t) * 256 + j];
}

// ---------------------------------------------------------------------------
// gemm_x: G[m][n] = sum_k X[m][k] * W4T[n][k]  (fp16 MFMA 16x16x32, 128x128)
// ---------------------------------------------------------------------------
__global__ __launch_bounds__(256) void gemm_x(const float* __restrict__ X,
                                              const _Float16* __restrict__ W4T,
                                              _Float16* __restrict__ G) {
    __shared__ __align__(16) _Float16 As[128][40];
    __shared__ __align__(16) _Float16 Bs[128][40];

    const int mt = blockIdx.x >> 3;
    const int nt = blockIdx.x & 7;
    const int m0 = mt * 128, n0 = nt * 128;
    const int tid  = threadIdx.x;
    const int lane = tid & 63, wave = tid >> 6;
    const int quad = lane >> 4, l16 = lane & 15;
    const int mq = (wave & 1) * 64, nq = (wave >> 1) * 64;

    floatx4 acc[4][4];
#pragma unroll
    for (int i = 0; i < 4; ++i)
#pragma unroll
        for (int j = 0; j < 4; ++j) acc[i][j] = (floatx4){0.f, 0.f, 0.f, 0.f};

    const int srow = tid >> 1;
    const int koff = (tid & 1) * 16;

    for (int kt = 0; kt < 7; ++kt) {
        const int k0 = kt * 32;
        {
            const int m = m0 + srow;
            const float* xr = X + (size_t)m * D_ + (k0 + koff);
            half8_t v0, v1;
            if (m < B_ * S_ - 1) {
                const floatx4* xp = (const floatx4*)xr;
                floatx4 f0 = xp[0], f1 = xp[1], f2 = xp[2], f3 = xp[3];
#pragma unroll
                for (int i = 0; i < 4; ++i) {
                    v0[i]     = (_Float16)f0[i];
                    v0[4 + i] = (_Float16)f1[i];
                    v1[i]     = (_Float16)f2[i];
                    v1[4 + i] = (_Float16)f3[i];
                }
            } else {
#pragma unroll
                for (int i = 0; i < 8; ++i) {
                    int k = k0 + koff + i;
                    v0[i] = (k < D_) ? (_Float16)xr[i] : (_Float16)0.f;
                }
#pragma unroll
                for (int i = 0; i < 8; ++i) {
                    int k = k0 + koff + 8 + i;
                    v1[i] = (k < D_) ? (_Float16)xr[8 + i] : (_Float16)0.f;
                }
            }
            *(half8_t*)&As[srow][koff]     = v0;
            *(half8_t*)&As[srow][koff + 8] = v1;
        }
        {
            const _Float16* wr = W4T + (size_t)(n0 + srow) * 224 + (k0 + koff);
            const half8_t* wp = (const half8_t*)wr;
            *(half8_t*)&Bs[srow][koff]     = wp[0];
            *(half8_t*)&Bs[srow][koff + 8] = wp[1];
        }
        __syncthreads();

        half8_t af[4], bf[4];
#pragma unroll
        for (int i = 0; i < 4; ++i) af[i] = *(const half8_t*)&As[mq + i * 16 + l16][quad * 8];
#pragma unroll
        for (int i = 0; i < 4; ++i) bf[i] = *(const half8_t*)&Bs[nq + i * 16 + l16][quad * 8];
#pragma unroll
        for (int mi = 0; mi < 4; ++mi)
#pragma unroll
            for (int ni = 0; ni < 4; ++ni)
                acc[mi][ni] = __builtin_amdgcn_mfma_f32_16x16x32_f16(af[mi], bf[ni], acc[mi][ni], 0, 0, 0);
        __syncthreads();
    }

#pragma unroll
    for (int mi = 0; mi < 4; ++mi)
#pragma unroll
        for (int ni = 0; ni < 4; ++ni)
#pragma unroll
            for (int r = 0; r < 4; ++r) {
                int grow = m0 + mq + mi * 16 + quad * 4 + r;
                int gcol = n0 + nq + ni * 16 + l16;
                G[(size_t)grow * 1024 + gcol] = (_Float16)acc[mi][ni][r];
            }
}

// ---------------------------------------------------------------------------
// lstm_rec: one workgroup (1024 threads = 16 waves) per batch row.
// Thread t owns gate-column n = t (gate g = t>>8, unit j = t&255).
// h broadcast: ONE ds_read_b64 per wave per step (lane l holds h[4l..4l+3]),
//   then v_readlane -> SGPR feeds v_dot2_f32_f16 directly. No per-chunk LDS
//   dependency chain (the round-3 stall).
// Wh k in [0,192): 96 pinned scalar VGPRs/thread (asm "+v").
// Wh k in [192,256): LDS, 128 KB, contiguous half8 layout WL8[c*1024 + col].
// ---------------------------------------------------------------------------
__global__ __launch_bounds__(1024) void lstm_rec(
    const _Float16* __restrict__ G,     // [B][S][1024] fp16
    const _Float16* __restrict__ WhT,   // [1024][256] fp16
    const float* __restrict__ bi, const float* __restrict__ bfg,
    const float* __restrict__ bo, const float* __restrict__ bz,
    const float* __restrict__ mask,     // [B][S] fp32
    float* __restrict__ out)            // [B][256] fp32
{
    extern __shared__ __align__(16) char smem[];
    _Float16* WL   = (_Float16*)smem;                    // 128 KB
    float*    act  = (float*)(smem + 131072);            // 4 KB
    _Float16* hbuf = (_Float16*)(smem + 131072 + 4096);  // 512 B

    const int b    = blockIdx.x;
    const int t    = threadIdx.x;   // 0..1023 == gate-column
    const int gate = t >> 8;
    const int lane = t & 63;

    // ---- stage LDS weight slice: WL8[c*1024 + t] = WhT[t][192+8c .. +7] ----
    half8_t* WL8 = (half8_t*)WL;
    {
        const half8_t* wsrc = (const half8_t*)(WhT + (size_t)t * 256 + 192);
#pragma unroll
        for (int i = 0; i < 8; ++i) WL8[i * 1024 + t] = wsrc[i];
    }

    // ---- register weight slice: k in [0,192) = 96 dwords, pinned ----
    const u32x4* pw = (const u32x4*)(WhT + (size_t)t * 256);
#define DECLW(i) unsigned w##i##_0, w##i##_1, w##i##_2, w##i##_3
#define LOADW(i) do { u32x4 _tmp = pw[i];                                     \
        w##i##_0 = _tmp[0]; w##i##_1 = _tmp[1];                               \
        w##i##_2 = _tmp[2]; w##i##_3 = _tmp[3];                               \
        asm volatile("" : "+v"(w##i##_0), "+v"(w##i##_1),                     \
                          "+v"(w##i##_2), "+v"(w##i##_3)); } while (0)
    DECLW(0);  DECLW(1);  DECLW(2);  DECLW(3);  DECLW(4);  DECLW(5);
    DECLW(6);  DECLW(7);  DECLW(8);  DECLW(9);  DECLW(10); DECLW(11);
    DECLW(12); DECLW(13); DECLW(14); DECLW(15); DECLW(16); DECLW(17);
    DECLW(18); DECLW(19); DECLW(20); DECLW(21); DECLW(22); DECLW(23);
    LOADW(0);  LOADW(1);  LOADW(2);  LOADW(3);  LOADW(4);  LOADW(5);
    LOADW(6);  LOADW(7);  LOADW(8);  LOADW(9);  LOADW(10); LOADW(11);
    LOADW(12); LOADW(13); LOADW(14); LOADW(15); LOADW(16); LOADW(17);
    LOADW(18); LOADW(19); LOADW(20); LOADW(21); LOADW(22); LOADW(23);

    const float bias = ((gate == 0) ? bi : (gate == 1) ? bfg
                        : (gate == 2) ? bo : bz)[t & 255];

    if (t < 256) hbuf[t] = (_Float16)0.f;
    __syncthreads();

    float c = 0.f, acc = 0.f, msum = 0.f;
    const _Float16* Gb = G + (size_t)b * S_ * 1024;
    const float*    mb = mask + (size_t)b * S_;
    const unsigned* hb32 = (const unsigned*)hbuf;

    // RL(c): half2 {h[2c], h[2c+1]} broadcast to all lanes via readlane.
    // hcx holds chunk 2*lane, hcy holds chunk 2*lane+1.
#define RL(c) __builtin_amdgcn_readlane((int)(((c) & 1) ? hcy : hcx), (c) >> 1)
#define RCHUNK(i) do {                                                        \
        a0 = fdot2f(bc_h2((unsigned)RL(4*(i)+0)), bc_h2(w##i##_0), a0);       \
        a1 = fdot2f(bc_h2((unsigned)RL(4*(i)+1)), bc_h2(w##i##_1), a1);       \
        a2 = fdot2f(bc_h2((unsigned)RL(4*(i)+2)), bc_h2(w##i##_2), a2);       \
        a3 = fdot2f(bc_h2((unsigned)RL(4*(i)+3)), bc_h2(w##i##_3), a3);       \
    } while (0)
#define LCHUNK(C) do {                                                        \
        half8_t wv = WL8[(C) * 1024 + t];                                     \
        a0 = fdot2f(bc_h2((unsigned)RL(96+4*(C)+0)), (half2_t){wv[0], wv[1]}, a0); \
        a1 = fdot2f(bc_h2((unsigned)RL(96+4*(C)+1)), (half2_t){wv[2], wv[3]}, a1); \
        a2 = fdot2f(bc_h2((unsigned)RL(96+4*(C)+2)), (half2_t){wv[4], wv[5]}, a2); \
        a3 = fdot2f(bc_h2((unsigned)RL(96+4*(C)+3)), (half2_t){wv[6], wv[7]}, a3); \
    } while (0)

    for (int s = 0; s < S_; ++s) {
        // one LDS read per wave: lane l takes h2 chunks 2l and 2l+1
        const u32x2 hc = *(const u32x2*)(hb32 + 2 * lane);
        const unsigned hcx = hc[0], hcy = hc[1];
        // global loads issued early; consumed ~1500 cycles later
        const float g0 = (float)Gb[((size_t)s << 10) + t];
        const float m  = mb[s];

        float a0 = 0.f, a1 = 0.f, a2 = 0.f, a3 = 0.f;
        RCHUNK(0);  RCHUNK(1);  RCHUNK(2);  RCHUNK(3);  RCHUNK(4);  RCHUNK(5);
        RCHUNK(6);  RCHUNK(7);  RCHUNK(8);  RCHUNK(9);  RCHUNK(10); RCHUNK(11);
        RCHUNK(12); RCHUNK(13); RCHUNK(14); RCHUNK(15); RCHUNK(16); RCHUNK(17);
        RCHUNK(18); RCHUNK(19); RCHUNK(20); RCHUNK(21); RCHUNK(22); RCHUNK(23);
        LCHUNK(0); LCHUNK(1); LCHUNK(2); LCHUNK(3);
        LCHUNK(4); LCHUNK(5); LCHUNK(6); LCHUNK(7);

        const float p = bias + g0 + ((a0 + a1) + (a2 + a3));
        // one transcendental per thread: gates i,f,o -> sigmoid; z -> tanh
        const float v = (gate < 3) ? fast_sig(p) : fast_tanh(p);
        act[t] = v;
        __syncthreads();
        if (t < 256) {
            const float fi = v;             // own value: sig(i)
            const float ff = act[256 + t];  // sig(f)
            const float fo = act[512 + t];  // sig(o)
            const float fz = act[768 + t];  // tanh(z)
            c = fi * fz + ff * c;
            const float h = fo * fast_tanh(c);
            acc  += m * h;
            msum += m;
            hbuf[t] = (_Float16)h;
        }
        __syncthreads();
    }
#undef RL
#undef RCHUNK
#undef LCHUNK
#undef DECLW
#undef LOADW
    if (t < 256) out[b * 256 + t] = acc / msum;
}

extern "C" void kernel_launch(void* const* d_in, const int* in_sizes, int n_in,
                              void* d_out, int out_size, void* d_ws, size_t ws_size,
                              hipStream_t stream) {
    const float* X    = (const float*)d_in[0];
    const float* mask = (const float*)d_in[1];
    const float* Wi   = (const float*)d_in[2];
    const float* bi   = (const float*)d_in[3];
    const float* Wf   = (const float*)d_in[4];
    const float* bf   = (const float*)d_in[5];
    const float* Wo   = (const float*)d_in[6];
    const float* bo   = (const float*)d_in[7];
    const float* Wz   = (const float*)d_in[8];
    const float* bz   = (const float*)d_in[9];
    float* out = (float*)d_out;

    char* ws = (char*)d_ws;
    _Float16* G   = (_Float16*)ws;                                   // 268,435,456 B
    _Float16* W4T = (_Float16*)(ws + (size_t)B_ * S_ * 1024 * 2);    //     458,752 B
    _Float16* WhT = (_Float16*)(ws + (size_t)B_ * S_ * 1024 * 2 + (size_t)1024 * 224 * 2);

    hipLaunchKernelGGL(prep,     dim3(1024), dim3(256), 0, stream, Wi, Wf, Wo, Wz, W4T, WhT);
    hipLaunchKernelGGL(gemm_x,   dim3(8192), dim3(256), 0, stream, X, W4T, G);
    hipLaunchKernelGGL(lstm_rec, dim3(B_),   dim3(1024), 131072 + 4096 + 512, stream,
                       G, WhT, bi, bf, bo, bz, mask, out);
}